// Round 6
// baseline (75.862 us; speedup 1.0000x reference)
//
#include <hip/hip_runtime.h>
#include <hip/hip_bf16.h>

#define B_ 64
#define N_ 576
#define D_ 384
#define K_ 4096
#define CPB 16              // chunks (blocks) per batch
#define RPB (N_ / CPB)      // 36 rows per chunk

// Single fused kernel, fence-free, FULL-WIDTH phase 2.
// Phase 1: block g=(b,c) projects its 36 rows into y via agent-scope sc1
//   write-through stores (L3 = device coherence point; R5-validated).
//   Software-pipelined z loads (R4 structure). Pair indices for phase 2 are
//   preloaded into registers here.
// Signal: s_waitcnt vmcnt(0) (y complete at L3) -> relaxed agent atomicAdd
//   on ctr[b]. NO __threadfence anywhere (R3: per-block fence = L2 writeback
//   walk, ~92us for 1024 blocks).
// Phase 2: ALL blocks participate (R5's 64-winner tail was the loss): block
//   (b,c) spins (tid0 only, s_sleep) until ctr[b]==16, then gathers its own
//   256 pairs, 1 pair/thread, reading y via agent-scope loads (bypass L1/L2,
//   served from L3 -- stale-L2-proof).
// Deadlock-safe spin: 1024 blocks, 256 thr, ~90 VGPR -> all co-resident
//   (capacity 8 blocks/CU, we use 4).
__global__ __launch_bounds__(256) void partvit_fused(const float* __restrict__ z,
                                                     const int* __restrict__ idx,
                                                     const float* __restrict__ W,
                                                     const float* __restrict__ bias,
                                                     float* __restrict__ out,
                                                     float* __restrict__ idx_out,
                                                     unsigned long long* __restrict__ y,
                                                     unsigned int* __restrict__ ctr) {
    const int g = blockIdx.x;
    const int b = g >> 4;     // batch
    const int c = g & 15;     // chunk within batch
    const int tid = threadIdx.x;
    const int hw = tid >> 5;  // half-wave 0..7
    const int s  = tid & 31;  // column-chunk owner
    const int c4 = s * 3;

    // Preload this thread's phase-2 pair (kept in registers; overlaps phase 1).
    const int t_out = b * K_ + c * 256 + tid;
    const int2 p = reinterpret_cast<const int2*>(idx)[t_out];
    const float b0 = bias[0], b1 = bias[1];

    const float4* Wq = reinterpret_cast<const float4*>(W);
    const float4* zq = reinterpret_cast<const float4*>(z);
    const int row0 = b * N_ + c * RPB;

    // ---- Phase 1: project rows hw, hw+8, ... (<36), software-pipelined ----
    int r = hw;
    float4 v0, v1, v2;
    {
        const float4* zr = zq + (size_t)(row0 + r) * 96 + c4;
        v0 = zr[0]; v1 = zr[1]; v2 = zr[2];
    }
    while (true) {
        const int rn = r + 8;
        const bool hn = rn < RPB;
        float4 n0, n1, n2;
        if (hn) {
            const float4* zn = zq + (size_t)(row0 + rn) * 96 + c4;
            n0 = zn[0]; n1 = zn[1]; n2 = zn[2];   // in flight during math below
        }

        // W[t][f] at t*768+f. float4: W0[:384]=Wq[0..95], W0[384:]=Wq[96..191],
        //                             W1[:384]=Wq[192..287], W1[384:]=Wq[288..383]
        float a0, a1, a2, a3;
        {
            const float4 wa = Wq[c4],     wb = Wq[c4+1],     wc = Wq[c4+2];
            a0 = v0.x*wa.x + v0.y*wa.y + v0.z*wa.z + v0.w*wa.w
               + v1.x*wb.x + v1.y*wb.y + v1.z*wb.z + v1.w*wb.w
               + v2.x*wc.x + v2.y*wc.y + v2.z*wc.z + v2.w*wc.w;
        }
        {
            const float4 wa = Wq[192+c4], wb = Wq[192+c4+1],  wc = Wq[192+c4+2];
            a1 = v0.x*wa.x + v0.y*wa.y + v0.z*wa.z + v0.w*wa.w
               + v1.x*wb.x + v1.y*wb.y + v1.z*wb.z + v1.w*wb.w
               + v2.x*wc.x + v2.y*wc.y + v2.z*wc.z + v2.w*wc.w;
        }
        {
            const float4 wa = Wq[96+c4],  wb = Wq[96+c4+1],   wc = Wq[96+c4+2];
            a2 = v0.x*wa.x + v0.y*wa.y + v0.z*wa.z + v0.w*wa.w
               + v1.x*wb.x + v1.y*wb.y + v1.z*wb.z + v1.w*wb.w
               + v2.x*wc.x + v2.y*wc.y + v2.z*wc.z + v2.w*wc.w;
        }
        {
            const float4 wa = Wq[288+c4], wb = Wq[288+c4+1],  wc = Wq[288+c4+2];
            a3 = v0.x*wa.x + v0.y*wa.y + v0.z*wa.z + v0.w*wa.w
               + v1.x*wb.x + v1.y*wb.y + v1.z*wb.z + v1.w*wb.w
               + v2.x*wc.x + v2.y*wc.y + v2.z*wc.z + v2.w*wc.w;
        }

#pragma unroll
        for (int off = 16; off > 0; off >>= 1) {
            a0 += __shfl_xor(a0, off);
            a1 += __shfl_xor(a1, off);
            a2 += __shfl_xor(a2, off);
            a3 += __shfl_xor(a3, off);
        }
        if (s == 0) {
            union { float2 f; unsigned long long u; } u0, u1;
            u0.f = make_float2(a0, a1);
            u1.f = make_float2(a2, a3);
            const size_t row2 = (size_t)(row0 + r) * 2;
            __hip_atomic_store(&y[row2 + 0], u0.u,
                               __ATOMIC_RELAXED, __HIP_MEMORY_SCOPE_AGENT);
            __hip_atomic_store(&y[row2 + 1], u1.u,
                               __ATOMIC_RELAXED, __HIP_MEMORY_SCOPE_AGENT);
        }

        if (!hn) break;
        r = rn;
        v0 = n0; v1 = n1; v2 = n2;
    }

    // ---- Signal: y stores complete at L3, then count this chunk ----
    asm volatile("s_waitcnt vmcnt(0)" ::: "memory");
    __syncthreads();
    if (tid == 0) {
        __hip_atomic_fetch_add(&ctr[b], 1u,
                               __ATOMIC_RELAXED, __HIP_MEMORY_SCOPE_AGENT);
        // Spin until all 16 chunks of batch b are done (all blocks resident).
        while (__hip_atomic_load(&ctr[b], __ATOMIC_RELAXED,
                                 __HIP_MEMORY_SCOPE_AGENT) < CPB) {
            __builtin_amdgcn_s_sleep(1);
        }
    }
    __syncthreads();
    asm volatile("" ::: "memory");   // keep y loads below the spin

    // ---- Phase 2: every block gathers its own 256 pairs (1/thread) ----
    const unsigned long long* yb = y + (size_t)b * N_ * 2;
    union { float2 f; unsigned long long u; } q0, q1;
    q0.u = __hip_atomic_load(&yb[(size_t)p.x * 2 + 0],
                             __ATOMIC_RELAXED, __HIP_MEMORY_SCOPE_AGENT);
    q1.u = __hip_atomic_load(&yb[(size_t)p.y * 2 + 1],
                             __ATOMIC_RELAXED, __HIP_MEMORY_SCOPE_AGENT);
    float2 o;
    o.x = q0.f.x + q1.f.x + b0;
    o.y = q0.f.y + q1.f.y + b1;
    reinterpret_cast<float2*>(out)[t_out] = o;
    float2 io;
    io.x = (float)p.x;
    io.y = (float)p.y;
    reinterpret_cast<float2*>(idx_out)[t_out] = io;
}

extern "C" void kernel_launch(void* const* d_in, const int* in_sizes, int n_in,
                              void* d_out, int out_size, void* d_ws, size_t ws_size,
                              hipStream_t stream) {
    const float* z    = (const float*)d_in[0];
    const int*   idx  = (const int*)d_in[1];
    const float* W    = (const float*)d_in[2];
    const float* bias = (const float*)d_in[3];

    float* out     = (float*)d_out;                        // [B,K,2] floats
    float* idx_out = (float*)d_out + (size_t)B_ * K_ * 2;  // indices as float
    unsigned long long* y = (unsigned long long*)d_ws;     // [B*N][2] = 576 KB
    unsigned int* ctr = (unsigned int*)((char*)d_ws + (1 << 20));  // 64 counters

    // Counters must be 0 at kernel start EVERY call (they end at 16).
    hipMemsetAsync(ctr, 0, B_ * sizeof(unsigned int), stream);

    // 16 blocks per batch x 64 batches = 1024 blocks, all co-resident
    partvit_fused<<<B_ * CPB, 256, 0, stream>>>(z, idx, W, bias,
                                                out, idx_out, y, ctr);
}

// Round 8
// 18.624 us; speedup vs baseline: 4.0734x; 4.0734x over previous
//
#include <hip/hip_runtime.h>
#include <hip/hip_bf16.h>

#define B_ 64
#define N_ 576
#define D_ 384
#define K_ 4096

// Kernel 1: per-row projection + idx pass-through.
//   y[r] = { z_r.W0[:384], z_r.W1[:384], z_r.W0[384:], z_r.W1[384:] }
//   idx_out[i] = (float)idx[i]   (independent of y; hidden under z streaming)
// Half-wave (32 lanes) per row; lane s owns float4-columns 3s..3s+2.
// Software-pipelined z loads (R4 structure, best measured: 18.7us total).
// 2048 blocks = 8192 waves = 32 waves/CU.
// R7 lesson: idx/idx_out have only (B*K*2)/2 = 262144 int2/float2 elements --
// guard the pass-through to the first 262144 threads (R7 crashed OOB).
__global__ __launch_bounds__(256) void partvit_proj(const float* __restrict__ z,
                                                    const int* __restrict__ idx,
                                                    const float* __restrict__ W,
                                                    float* __restrict__ y,
                                                    float* __restrict__ idx_out) {
    const int gid  = blockIdx.x * blockDim.x + threadIdx.x;
    const int wid  = gid >> 6;
    const int lane = threadIdx.x & 63;
    const int h = lane >> 5;   // which row of the pair
    const int s = lane & 31;   // column-chunk owner within the row
    const int c4 = s * 3;

    // ---- idx pass-through: first 262144 threads, one int2 -> float2 each ----
    const int NIO = (B_ * K_ * 2) / 2;     // 262144 int2 elements total
    int2 pv;
    const bool do_io = gid < NIO;
    if (do_io) pv = reinterpret_cast<const int2*>(idx)[gid];  // issue early

    const float4* Wq = reinterpret_cast<const float4*>(W);
    const float4* zq = reinterpret_cast<const float4*>(z);

    const int npairs = (B_ * N_) / 2;                       // 18432 row-pairs
    const int nwaves = (gridDim.x * blockDim.x) >> 6;       // 8192

    int pid = wid;
    float4 v0, v1, v2;
    if (pid < npairs) {
        const float4* zr = zq + (size_t)(pid * 2 + h) * 96 + c4;
        v0 = zr[0]; v1 = zr[1]; v2 = zr[2];
    }

    if (do_io) {   // convert+store while the first z loads are in flight
        float2 io;
        io.x = (float)pv.x;
        io.y = (float)pv.y;
        reinterpret_cast<float2*>(idx_out)[gid] = io;
    }

    if (pid >= npairs) return;

    while (true) {
        const int next = pid + nwaves;
        const bool has_next = next < npairs;
        float4 n0, n1, n2;
        if (has_next) {
            const float4* zr = zq + (size_t)(next * 2 + h) * 96 + c4;
            n0 = zr[0]; n1 = zr[1]; n2 = zr[2];   // in flight during reduce below
        }

        // W[t][f] at t*768+f. float4: W0[:384]=Wq[0..95], W0[384:]=Wq[96..191],
        //                             W1[:384]=Wq[192..287], W1[384:]=Wq[288..383]
        float a0, a1, a2, a3;
        {
            const float4 wa = Wq[c4],     wb = Wq[c4+1],     wc = Wq[c4+2];
            a0 = v0.x*wa.x + v0.y*wa.y + v0.z*wa.z + v0.w*wa.w
               + v1.x*wb.x + v1.y*wb.y + v1.z*wb.z + v1.w*wb.w
               + v2.x*wc.x + v2.y*wc.y + v2.z*wc.z + v2.w*wc.w;
        }
        {
            const float4 wa = Wq[192+c4], wb = Wq[192+c4+1],  wc = Wq[192+c4+2];
            a1 = v0.x*wa.x + v0.y*wa.y + v0.z*wa.z + v0.w*wa.w
               + v1.x*wb.x + v1.y*wb.y + v1.z*wb.z + v1.w*wb.w
               + v2.x*wc.x + v2.y*wc.y + v2.z*wc.z + v2.w*wc.w;
        }
        {
            const float4 wa = Wq[96+c4],  wb = Wq[96+c4+1],   wc = Wq[96+c4+2];
            a2 = v0.x*wa.x + v0.y*wa.y + v0.z*wa.z + v0.w*wa.w
               + v1.x*wb.x + v1.y*wb.y + v1.z*wb.z + v1.w*wb.w
               + v2.x*wc.x + v2.y*wc.y + v2.z*wc.z + v2.w*wc.w;
        }
        {
            const float4 wa = Wq[288+c4], wb = Wq[288+c4+1],  wc = Wq[288+c4+2];
            a3 = v0.x*wa.x + v0.y*wa.y + v0.z*wa.z + v0.w*wa.w
               + v1.x*wb.x + v1.y*wb.y + v1.z*wb.z + v1.w*wb.w
               + v2.x*wc.x + v2.y*wc.y + v2.z*wc.z + v2.w*wc.w;
        }

        // reduce across the 32 lanes of this half-wave
#pragma unroll
        for (int off = 16; off > 0; off >>= 1) {
            a0 += __shfl_xor(a0, off);
            a1 += __shfl_xor(a1, off);
            a2 += __shfl_xor(a2, off);
            a3 += __shfl_xor(a3, off);
        }
        if (s == 0) {
            float4 o;
            o.x = a0; o.y = a1; o.z = a2; o.w = a3;
            reinterpret_cast<float4*>(y)[pid * 2 + h] = o;
        }

        if (!has_next) break;
        pid = next;
        v0 = n0; v1 = n1; v2 = n2;
    }
}

// Kernel 2: gather-only. 2 pairs/thread, int4 idx load, float4 out store.
//   out[b,k,t] = y[b,i0][t] + y[b,i1][2+t] + bias[t]
// Plain loads: the kernel boundary provides producer->consumer coherence
// (R3/R5/R6 showed every in-kernel alternative is 2.5-4x slower).
__global__ __launch_bounds__(256) void partvit_gather(const int* __restrict__ idx,
                                                      const float* __restrict__ y,
                                                      const float* __restrict__ bias,
                                                      float* __restrict__ out) {
    const int i = blockIdx.x * blockDim.x + threadIdx.x;  // 0..131071
    if (i >= (B_ * K_) / 2) return;
    const int b = i >> 11;  // 2048 int4-pairs per batch

    const int4 pp = reinterpret_cast<const int4*>(idx)[i];  // pairs 2i, 2i+1
    const float* yb = y + (size_t)b * N_ * 4;

    const float2 q0 = *reinterpret_cast<const float2*>(yb + (size_t)pp.x * 4);
    const float2 q1 = *reinterpret_cast<const float2*>(yb + (size_t)pp.y * 4 + 2);
    const float2 q2 = *reinterpret_cast<const float2*>(yb + (size_t)pp.z * 4);
    const float2 q3 = *reinterpret_cast<const float2*>(yb + (size_t)pp.w * 4 + 2);

    const float b0 = bias[0], b1 = bias[1];
    float4 o;
    o.x = q0.x + q1.x + b0;
    o.y = q0.y + q1.y + b1;
    o.z = q2.x + q3.x + b0;
    o.w = q2.y + q3.y + b1;
    reinterpret_cast<float4*>(out)[i] = o;
}

extern "C" void kernel_launch(void* const* d_in, const int* in_sizes, int n_in,
                              void* d_out, int out_size, void* d_ws, size_t ws_size,
                              hipStream_t stream) {
    const float* z    = (const float*)d_in[0];
    const int*   idx  = (const int*)d_in[1];
    const float* W    = (const float*)d_in[2];
    const float* bias = (const float*)d_in[3];

    float* out     = (float*)d_out;                        // [B,K,2] floats
    float* idx_out = (float*)d_out + (size_t)B_ * K_ * 2;  // indices as float
    float* y       = (float*)d_ws;                         // [B*N,4] floats = 576 KB

    // Kernel 1: 8192 waves grid-striding over 18432 row-pairs + idx pass-through
    partvit_proj<<<2048, 256, 0, stream>>>(z, idx, W, y, idx_out);

    // Kernel 2: 131072 threads, 2 pairs each -> 512 blocks
    partvit_gather<<<512, 256, 0, stream>>>(idx, y, bias, out);
}